// Round 7
// baseline (296.509 us; speedup 1.0000x reference)
//
#include <hip/hip_runtime.h>

// ConditionalFeedForward (gpt-fast MoE FFN), MI355X. fp32 in/out.
//   x[T][H], idx[T][K], gate[E][I][H], up[E][H][I], down[E][I][H]
//   hbuf[p][o] = silu(x.gate_row) * (x.down_row);  out[p][h] = hbuf[p].up_row
// R11 == R10 resubmit (R10 bench died on container acquisition, no counters).
// R10 theory: dur model = phase1 + phase2 + ~169us fixed harness overhead.
// Both phases pinned at ~2.45 TB/s combined L3+HBM service across 6
// structural variants (occupancy 10-72%, burst 8-32KB, NT, swizzle: all
// invariant). Copy hits 6.3 TB/s -> not a fabric limit. The constant was the
// SHAPE: per-wave burst -> consume -> serial wave-sum. R10 transposes to
// GEMV-T: lanes OWN outputs (P1: 4 rows x 16 lane-groups/wave; P2: 2 x 32),
// pure weight-load->FMA stream per lane, x staged in LDS (out of the vmcnt
// stream), one small end butterfly. Pairs zero-padded to 8: branch-free loop.
#define NE 8
#define HD 1024
#define IW 2816
#define NT 16
#define TK 2
#define NP (NT*TK)
#define NPC 8           // padded pair chunk (both phases); npl>8 ~2% re-streams

// Phase 1: block = 4 waves x 4 o-rows = 16 rows; grid.x = IW/16 = 176.
// lane = (rloc<<4)|kg: row o0+wave*4+rloc, k-slice = f4 indices {kg+16*s}.
__global__ __launch_bounds__(256) void moe_phase1(
    const float* __restrict__ x,      // [NT][HD]
    const int*   __restrict__ idx,    // [NT][TK]
    const float* __restrict__ gate,   // [NE][IW][HD]
    const float* __restrict__ down,   // [NE][IW][HD]
    float*       __restrict__ hbuf)   // [NP][IW]
{
    __shared__ float s_x[NPC][HD];    // 32 KB
    __shared__ int s_list[NP];
    __shared__ int s_n;
    const int e = blockIdx.y;
    {
        const int t = threadIdx.x;
        const bool mine = (t < NP) && (idx[t] == e);
        const unsigned long long m = __ballot(mine);
        if (mine) s_list[__popcll(m & ((1ull << t) - 1ull))] = t;
        if (t == 0) s_n = (int)__popcll(m);
    }
    __syncthreads();
    const int npl = s_n;
    if (npl == 0) return;

    const int wave = threadIdx.x >> 6;
    const int lane = threadIdx.x & 63;
    const int rloc = lane >> 4;                       // 0..3
    const int kg   = lane & 15;                       // 0..15
    const int orow = blockIdx.x * 16 + wave * 4 + rloc;

    const float* gp = gate + ((size_t)e * IW + orow) * HD + kg * 4;
    const float* dp = down + ((size_t)e * IW + orow) * HD + kg * 4;

    for (int g0 = 0; g0 < npl; g0 += NPC) {
        const int nc = (npl - g0 < NPC) ? (npl - g0) : NPC;
        __syncthreads();                              // s_x reuse barrier
        {
            const int t = threadIdx.x;
            #pragma unroll
            for (int j = 0; j < NPC; ++j) {           // 1 f4 per thread per row
                if (j < nc) {
                    const int tok = s_list[g0 + j] >> 1;   // TK==2
                    *(float4*)&s_x[j][t * 4] = *(const float4*)(x + (size_t)tok * HD + t * 4);
                } else {
                    *(float4*)&s_x[j][t * 4] = make_float4(0.f, 0.f, 0.f, 0.f);
                }
            }
        }
        __syncthreads();

        float ag[NPC], ad[NPC];
        #pragma unroll
        for (int j = 0; j < NPC; ++j) { ag[j] = 0.f; ad[j] = 0.f; }

        #pragma unroll 4
        for (int s = 0; s < 16; ++s) {                // 16 f4-steps per lane
            const float4 g4 = *(const float4*)(gp + s * 64);   // 64 floats = 16 f4
            const float4 d4 = *(const float4*)(dp + s * 64);
            #pragma unroll
            for (int j = 0; j < NPC; ++j) {
                const float4 x4 = *(const float4*)&s_x[j][s * 64 + kg * 4];
                ag[j] += g4.x*x4.x + g4.y*x4.y + g4.z*x4.z + g4.w*x4.w;
                ad[j] += d4.x*x4.x + d4.y*x4.y + d4.z*x4.z + d4.w*x4.w;
            }
        }
        // butterfly within each 16-lane group, level-major
        #pragma unroll
        for (int off = 1; off < 16; off <<= 1) {
            #pragma unroll
            for (int j = 0; j < NPC; ++j) {
                ag[j] += __shfl_xor(ag[j], off, 64);
                ad[j] += __shfl_xor(ad[j], off, 64);
            }
        }
        if (kg == 0) {
            #pragma unroll
            for (int j = 0; j < NPC; ++j) {
                if (j < nc) {
                    const float g = ag[j];
                    const float sg = g / (1.f + __expf(-g));   // silu
                    hbuf[(size_t)s_list[g0 + j] * IW + orow] = sg * ad[j];
                }
            }
        }
    }
}

// Phase 2: block = 4 waves x 2 h-rows = 8 rows; grid.x = HD/8 = 128.
// lane = (rloc<<5)|kg: row h0+wave*2+rloc, k-slice = f4 indices {kg+32*s},
// 22 steps (704 f4 / 32). hbuf read direct (L1/L2-hot, 16B broadcast/group).
__global__ __launch_bounds__(256) void moe_phase2(
    const float* __restrict__ up,     // [NE][HD][IW]
    const int*   __restrict__ idx,
    const float* __restrict__ hbuf,   // [NP][IW]
    float*       __restrict__ out)    // [NP][HD]
{
    __shared__ int s_list[NP];
    __shared__ int s_n;
    const int e = blockIdx.y;
    {
        const int t = threadIdx.x;
        const bool mine = (t < NP) && (idx[t] == e);
        const unsigned long long m = __ballot(mine);
        if (mine) s_list[__popcll(m & ((1ull << t) - 1ull))] = t;
        if (t == 0) s_n = (int)__popcll(m);
    }
    __syncthreads();
    const int npl = s_n;
    if (npl == 0) return;

    const int wave = threadIdx.x >> 6;
    const int lane = threadIdx.x & 63;
    const int rloc = lane >> 5;                       // 0..1
    const int kg   = lane & 31;                       // 0..31
    const int hrow = blockIdx.x * 8 + wave * 2 + rloc;

    const float* upp = up + ((size_t)e * HD + hrow) * IW + kg * 4;

    for (int g0 = 0; g0 < npl; g0 += NPC) {
        const int nc = (npl - g0 < NPC) ? (npl - g0) : NPC;
        const float* hp[NPC];
        #pragma unroll
        for (int j = 0; j < NPC; ++j) {
            const int p = s_list[g0 + (j < nc ? j : 0)];    // clamp: safe addr
            hp[j] = hbuf + (size_t)p * IW + kg * 4;
        }

        float acc[NPC];
        #pragma unroll
        for (int j = 0; j < NPC; ++j) acc[j] = 0.f;

        #pragma unroll 2
        for (int s = 0; s < 22; ++s) {                // 22 f4-steps per lane
            const float4 u4 = *(const float4*)(upp + s * 128);  // 128 floats = 32 f4
            #pragma unroll
            for (int j = 0; j < NPC; ++j) {
                const float4 h4 = *(const float4*)(hp[j] + s * 128);
                acc[j] += u4.x*h4.x + u4.y*h4.y + u4.z*h4.z + u4.w*h4.w;
            }
        }
        #pragma unroll
        for (int off = 1; off < 32; off <<= 1) {
            #pragma unroll
            for (int j = 0; j < NPC; ++j)
                acc[j] += __shfl_xor(acc[j], off, 64);
        }
        if (kg == 0) {
            #pragma unroll
            for (int j = 0; j < NPC; ++j)
                if (j < nc) out[(size_t)s_list[g0 + j] * HD + hrow] = acc[j];
        }
    }
}

extern "C" void kernel_launch(void* const* d_in, const int* in_sizes, int n_in,
                              void* d_out, int out_size, void* d_ws, size_t ws_size,
                              hipStream_t stream) {
    const float* x    = (const float*)d_in[0];
    const int*   idx  = (const int*)  d_in[1];
    const float* gate = (const float*)d_in[2];
    const float* up   = (const float*)d_in[3];
    const float* down = (const float*)d_in[4];
    float* hbuf = (float*)d_ws;              // 32*2816*4 = 360448 B scratch
    float* out  = (float*)d_out;             // [16][2][1024]

    moe_phase1<<<dim3(IW / 16, NE), dim3(256), 0, stream>>>(x, idx, gate, down, hbuf);
    moe_phase2<<<dim3(HD / 8, NE), dim3(256), 0, stream>>>(up, idx, hbuf, out);
}